// Round 8
// baseline (287.615 us; speedup 1.0000x reference)
//
#include <hip/hip_runtime.h>
#include <stdint.h>

// ---------------------------------------------------------------------------
// SelfAttentiveBimodalFusion: MLP(192->16->16) -> Q(8),K(8),V(64) -> full
// N x N attention -> out (N,64).  N = 12288.  fp32 in / fp32 out.
// Validated r5-r7: absmax 9.8e-4 vs thr 2.7e-3.
//
// r7 counters: k2 bound by vector-memory REQUEST rate: V^T loads had lane
// stride 24 KB -> 64 lines per instruction, ~576 lane-requests/iter ->
// ~125 us of TA occupancy (matches 143 us measured; VALU 16%, MFMA 7%,
// HBM 3% all idle).
// r8: V stored key-TILED ([key/32][c][key%32], 72-B padded rows, 4608-B
// tiles); k2 stages each wave's tile global->LDS with coalesced uint4
// loads (5 instrs, ~25 requests/iter), wave-private double buffer (no
// barriers), ds_read_b64 fragment gather.  Fragment/relabel algebra is
// byte-identical to the r5-validated kernel; only the address source
// changes.  Epilogue reduce reuses (aliases) the staging LDS.
// ---------------------------------------------------------------------------

#define NN 12288

typedef float    f32x16 __attribute__((ext_vector_type(16)));
typedef short    s16x8  __attribute__((ext_vector_type(8)));
typedef unsigned short u16;

#define MFMA_32x32x16_BF16 __builtin_amdgcn_mfma_f32_32x32x16_bf16

// ws layout (bytes)
#define OFF_QB   0u          // N*8*2   = 196608  (bf16, pre-scaled)
#define OFF_KB   196608u     // N*8*2   = 196608  (bf16)
#define OFF_VT   393216u     // 384 tiles * 4608 B = 1769472 (bf16 V, tiled)
#define OFF_WF   2162688u    // 4608*4  = 18432   (fp32 weights)
#define OFF_FLAG 2181120u    // 4 (+pad)
#define OFF_PO   2181376u    // S*N*64*4 fp32 O partials; pl follows (S*N*4)

__device__ __forceinline__ float bf2f(u16 s) {
    union { unsigned int u; float f; } c; c.u = ((unsigned int)s) << 16; return c.f;
}
__device__ __forceinline__ u16 f2bf(float f) {
    union { float f; unsigned int u; } c; c.f = f;
    return (u16)((c.u + 0x8000u) >> 16);
}
__device__ __forceinline__ unsigned int pk2(float a, float b) {
    union { float f; unsigned int u; } ca, cb; ca.f = a; cb.f = b;
    return ((ca.u + 0x8000u) >> 16) | ((cb.u + 0x8000u) & 0xffff0000u);
}
__device__ __forceinline__ f32x16 zf16() {
    f32x16 z;
#pragma unroll
    for (int i = 0; i < 16; ++i) z[i] = 0.f;
    return z;
}
__device__ __forceinline__ s16x8 zs8() {
    s16x8 z;
#pragma unroll
    for (int i = 0; i < 8; ++i) z[i] = 0;
    return z;
}

union U8 { s16x8 v; unsigned int u[4]; };

// ------------------ kernel 0: detect dtype + convert weights ----------------
__global__ __launch_bounds__(256) void k0_init(
    const void* __restrict__ we1, const void* __restrict__ we2,
    const void* __restrict__ wq,  const void* __restrict__ wk,
    const void* __restrict__ wv,  const void* __restrict__ xmod,
    float* __restrict__ wf, int* __restrict__ flag)
{
    int t = threadIdx.x;
    __shared__ int cnt;
    if (t == 0) cnt = 0;
    __syncthreads();
    {
        const u16* xm16 = (const u16*)xmod;
        float v = bf2f(xm16[2 * t]);
        if (fabsf(v) > 16.f) atomicAdd(&cnt, 1);
    }
    __syncthreads();
    const int isf32 = (cnt > 8);
    if (t == 0) flag[0] = isf32;

    const float SCL = 0.51006979f;       // (1/sqrt(8)) * log2(e)
    if (isf32) {
        const float* a1 = (const float*)we1; const float* a2 = (const float*)we2;
        const float* aq = (const float*)wq;  const float* ak = (const float*)wk;
        const float* av = (const float*)wv;
        for (int i = t; i < 4608; i += 256) {
            if      (i < 3072) wf[i] = a1[i];
            else if (i < 3328) wf[i] = a2[i - 3072];
            else if (i < 3456) wf[i] = aq[i - 3328] * SCL;
            else if (i < 3584) wf[i] = ak[i - 3456];
            else               wf[i] = av[i - 3584];
        }
    } else {
        const u16* a1 = (const u16*)we1; const u16* a2 = (const u16*)we2;
        const u16* aq = (const u16*)wq;  const u16* ak = (const u16*)wk;
        const u16* av = (const u16*)wv;
        for (int i = t; i < 4608; i += 256) {
            if      (i < 3072) wf[i] = bf2f(a1[i]);
            else if (i < 3328) wf[i] = bf2f(a2[i - 3072]);
            else if (i < 3456) wf[i] = bf2f(aq[i - 3328]) * SCL;
            else if (i < 3584) wf[i] = bf2f(ak[i - 3456]);
            else               wf[i] = bf2f(av[i - 3584]);
        }
    }
}

// --------------------------- kernel 1: MLP -> Qb, Kb, Vt(tiled) -------------
__global__ __launch_bounds__(256) void k1_qkv(
    const void* __restrict__ xmain, const void* __restrict__ xmod,
    const float* __restrict__ wf, const int* __restrict__ flag,
    u16* __restrict__ qb, u16* __restrict__ kb, u16* __restrict__ vt)
{
    const int t = threadIdx.x;
    const int r = t >> 2;            // row in block, 0..63
    const int p = t & 3;             // part, 0..3
    const int row = blockIdx.x * 64 + r;

    const float* __restrict__ W1 = wf;          // [192][16]
    const float* __restrict__ W2 = wf + 3072;   // [16][16]
    const float* __restrict__ Wq = wf + 3328;   // [16][8] pre-scaled
    const float* __restrict__ Wk = wf + 3456;   // [16][8]
    const float* __restrict__ Wv = wf + 3584;   // [16][64]

    __shared__ float lh1[64][4][17];
    __shared__ float lh2[64][17];

    float h1p[16];
#pragma unroll
    for (int o = 0; o < 16; ++o) h1p[o] = 0.f;

    if (flag[0]) {
#pragma unroll
        for (int cc = 0; cc < 12; ++cc) {
            const int c = p + cc * 4;
            float4 xv = (c < 16)
                ? ((const float4*)xmain)[(size_t)row * 16 + c]
                : ((const float4*)xmod)[(size_t)row * 32 + (c - 16)];
            float xs[4] = {xv.x, xv.y, xv.z, xv.w};
#pragma unroll
            for (int j = 0; j < 4; ++j) {
                const float* wr = W1 + (c * 4 + j) * 16;
#pragma unroll
                for (int o = 0; o < 16; ++o) h1p[o] += xs[j] * wr[o];
            }
        }
    } else {
#pragma unroll
        for (int cc = 0; cc < 12; ++cc) {
            const int c = p + cc * 4;
            uint2 xv = (c < 16)
                ? ((const uint2*)xmain)[(size_t)row * 16 + c]
                : ((const uint2*)xmod)[(size_t)row * 32 + (c - 16)];
            float xs[4] = { bf2f((u16)(xv.x & 0xffff)), bf2f((u16)(xv.x >> 16)),
                            bf2f((u16)(xv.y & 0xffff)), bf2f((u16)(xv.y >> 16)) };
#pragma unroll
            for (int j = 0; j < 4; ++j) {
                const float* wr = W1 + (c * 4 + j) * 16;
#pragma unroll
                for (int o = 0; o < 16; ++o) h1p[o] += xs[j] * wr[o];
            }
        }
    }
#pragma unroll
    for (int o = 0; o < 16; ++o) lh1[r][p][o] = h1p[o];
    __syncthreads();

    float h1[16];
#pragma unroll
    for (int o = 0; o < 16; ++o)
        h1[o] = fmaxf(lh1[r][0][o] + lh1[r][1][o] + lh1[r][2][o] + lh1[r][3][o], 0.f);

#pragma unroll
    for (int oo = 0; oo < 4; ++oo) {
        const int o = p * 4 + oo;
        float s = 0.f;
#pragma unroll
        for (int j = 0; j < 16; ++j) s += h1[j] * W2[j * 16 + o];
        lh2[r][o] = fmaxf(s, 0.f);
    }
    __syncthreads();

    float h2[16];
#pragma unroll
    for (int j = 0; j < 16; ++j) h2[j] = lh2[r][j];

    {
        float q0 = 0.f, q1 = 0.f, k0 = 0.f, k1 = 0.f;
        const int o = 2 * p;
#pragma unroll
        for (int j = 0; j < 16; ++j) {
            q0 += h2[j] * Wq[j * 8 + o];
            q1 += h2[j] * Wq[j * 8 + o + 1];
            k0 += h2[j] * Wk[j * 8 + o];
            k1 += h2[j] * Wk[j * 8 + o + 1];
        }
        ((unsigned int*)qb)[(size_t)row * 4 + p] = pk2(q0, q1);
        ((unsigned int*)kb)[(size_t)row * 4 + p] = pk2(k0, k1);
    }

    // V store, key-tiled layout: [tile][c][kk], row stride 36 u16 (72 B)
    const int tI = row >> 5, kk = row & 31;
#pragma unroll
    for (int c16 = 0; c16 < 16; ++c16) {
        const int c = p * 16 + c16;
        float v = 0.f;
#pragma unroll
        for (int j = 0; j < 16; ++j) v += h2[j] * Wv[j * 64 + c];
        vt[(size_t)tI * 2304 + c * 36 + kk] = f2bf(v);
    }
}

// --------------------------- kernel 2: attention partials -------------------
// grid = 384 q-tiles * S key-splits; block = 4 waves; each wave sweeps its
// keys with LDS-staged (coalesced) V tiles, wave-private double buffer.
__global__ __launch_bounds__(256, 4) void k2_attn(
    const u16* __restrict__ qb, const u16* __restrict__ kb,
    const u16* __restrict__ vt,
    float* __restrict__ po, float* __restrict__ pl,
    int nsplit, int tiles)
{
    __shared__ uint4 smem4[2304];           // 36864 B: staging + epilogue union
    char* smem = (char*)smem4;

    const int tid  = threadIdx.x;
    const int lane = tid & 63;
    const int half = lane >> 5;
    const int l31  = lane & 31;
    const int w    = tid >> 6;              // wave 0..3
    const int qt   = blockIdx.x % 384;
    const int sp   = blockIdx.x / 384;
    const int qbase = qt * 32;
    const int key_start = sp * (NN / nsplit) + w * (tiles * 32);
    const int t0 = key_start >> 5;          // first V tile for this wave

    char* bufA = smem + w * 9216;
    char* bufB = bufA + 4608;

    const f32x16 Z = zf16();
    s16x8 qf = zs8();
    if (!half) qf = *(const s16x8*)(qb + (size_t)(qbase + l31) * 8);

    f32x16 acc0 = Z, acc1 = Z;
    float ls = 0.f;

    const char* gv = (const char*)vt;

    // stage tile 0 into bufA (coalesced: lanes -> consecutive 16-B chunks)
    {
        const char* g = gv + (size_t)t0 * 4608;
#pragma unroll
        for (int j = 0; j < 5; ++j) {
            const int id = j * 64 + lane;
            if (id < 288) *(uint4*)(bufA + id * 16) = *(const uint4*)(g + id * 16);
        }
    }

    for (int kt = 0; kt < tiles; ++kt) {
        // issue next tile's global loads (held in regs until end of iter)
        uint4 stg[5];
        const bool has_next = (kt + 1 < tiles);
        if (has_next) {
            const char* g = gv + (size_t)(t0 + kt + 1) * 4608;
#pragma unroll
            for (int j = 0; j < 5; ++j) {
                const int id = j * 64 + lane;
                if (id < 288) stg[j] = *(const uint4*)(g + id * 16);
            }
        }

        // S^T = K.Q^T (Q half1 zero -> one-sided qk pad)
        s16x8 ka = *(const s16x8*)(kb + (size_t)(key_start + kt * 32 + l31) * 8);
        f32x16 S = MFMA_32x32x16_BF16(ka, qf, Z, 0, 0, 0);

        float pr[16];
        float ls0 = 0.f, ls1 = 0.f;
#pragma unroll
        for (int r = 0; r < 8; ++r) {
            pr[r]     = __builtin_amdgcn_exp2f(S[r]);
            pr[r + 8] = __builtin_amdgcn_exp2f(S[r + 8]);
            ls0 += pr[r];
            ls1 += pr[r + 8];
        }
        ls += ls0 + ls1;

        U8 pb0, pb1;
#pragma unroll
        for (int i = 0; i < 4; ++i) {
            pb0.u[i] = pk2(pr[2 * i],     pr[2 * i + 1]);
            pb1.u[i] = pk2(pr[8 + 2 * i], pr[8 + 2 * i + 1]);
        }

        // A-fragments from LDS tile (same relabeling as r5-validated kernel):
        // row c bytes [32ks+8h, +8) and [32ks+8h+16, +8)
        const char* r0 = bufA + l31 * 72 + 8 * half;          // ct=0
        const char* r1 = bufA + (32 + l31) * 72 + 8 * half;   // ct=1
        U8 va;
        uint2 x0, x1;
        x0 = *(const uint2*)(r0);       x1 = *(const uint2*)(r0 + 16);
        va.u[0] = x0.x; va.u[1] = x0.y; va.u[2] = x1.x; va.u[3] = x1.y;
        acc0 = MFMA_32x32x16_BF16(va.v, pb0.v, acc0, 0, 0, 0);
        x0 = *(const uint2*)(r1);       x1 = *(const uint2*)(r1 + 16);
        va.u[0] = x0.x; va.u[1] = x0.y; va.u[2] = x1.x; va.u[3] = x1.y;
        acc1 = MFMA_32x32x16_BF16(va.v, pb0.v, acc1, 0, 0, 0);
        x0 = *(const uint2*)(r0 + 32);  x1 = *(const uint2*)(r0 + 48);
        va.u[0] = x0.x; va.u[1] = x0.y; va.u[2] = x1.x; va.u[3] = x1.y;
        acc0 = MFMA_32x32x16_BF16(va.v, pb1.v, acc0, 0, 0, 0);
        x0 = *(const uint2*)(r1 + 32);  x1 = *(const uint2*)(r1 + 48);
        va.u[0] = x0.x; va.u[1] = x0.y; va.u[2] = x1.x; va.u[3] = x1.y;
        acc1 = MFMA_32x32x16_BF16(va.v, pb1.v, acc1, 0, 0, 0);

        // commit staged tile (wave-private: no barrier needed)
        if (has_next) {
#pragma unroll
            for (int j = 0; j < 5; ++j) {
                const int id = j * 64 + lane;
                if (id < 288) *(uint4*)(bufB + id * 16) = stg[j];
            }
        }
        char* tmp = bufA; bufA = bufB; bufB = tmp;
    }

    // ---- epilogue: reuse staging LDS for the 4-wave reduce ----
    __syncthreads();                        // all waves done with staging
    float (*lo)[64][33] = (float(*)[64][33])smem;        // 33792 B
    float (*ll)[32]     = (float(*)[32])(smem + 33792);  // 512 B

    ls += __shfl_xor(ls, 32, 64);
    if (lane < 32) ll[w][l31] = ls;
#pragma unroll
    for (int r = 0; r < 16; ++r) {
        const int c = (r & 3) + 8 * (r >> 2) + 4 * half;
        lo[w][c][l31]      = acc0[r];
        lo[w][32 + c][l31] = acc1[r];
    }
    __syncthreads();

    const int rq = tid >> 3;                // query 0..31
    const int c0 = (tid & 7) * 8;           // channel base
    float o[8];
#pragma unroll
    for (int j = 0; j < 8; ++j) {
        o[j] = lo[0][c0 + j][rq] + lo[1][c0 + j][rq] +
               lo[2][c0 + j][rq] + lo[3][c0 + j][rq];
    }
    float4* pov = (float4*)(po + (size_t)sp * (NN * 64) +
                            (size_t)(qbase + rq) * 64 + c0);
    pov[0] = make_float4(o[0], o[1], o[2], o[3]);
    pov[1] = make_float4(o[4], o[5], o[6], o[7]);
    if (tid < 32)
        pl[(size_t)sp * NN + qbase + tid] =
            ll[0][tid] + ll[1][tid] + ll[2][tid] + ll[3][tid];
}

// --------------------------- kernel 3: reduce splits + normalize ------------
__global__ __launch_bounds__(256) void k3_norm(
    const float4* __restrict__ po, const float* __restrict__ pl,
    float4* __restrict__ out, int nsplit)
{
    const int i = blockIdx.x * 256 + threadIdx.x;   // 196608 float4s
    const int row = i >> 4;
    float l = 0.f;
    float4 o = make_float4(0.f, 0.f, 0.f, 0.f);
    for (int s = 0; s < nsplit; ++s) {
        l += pl[(size_t)s * NN + row];
        float4 p = po[(size_t)s * (NN * 16) + i];
        o.x += p.x; o.y += p.y; o.z += p.z; o.w += p.w;
    }
    const float rl = 1.0f / l;
    out[i] = make_float4(o.x * rl, o.y * rl, o.z * rl, o.w * rl);
}

// ---------------------------------------------------------------------------
extern "C" void kernel_launch(void* const* d_in, const int* in_sizes, int n_in,
                              void* d_out, int out_size, void* d_ws, size_t ws_size,
                              hipStream_t stream)
{
    const void* xmain = d_in[0];
    const void* xmod  = d_in[1];
    // d_in[2] = xyz (unused by the reference)
    const void* we1   = d_in[3];
    const void* we2   = d_in[4];
    const void* wq    = d_in[5];
    const void* wk    = d_in[6];
    const void* wv    = d_in[7];

    char* ws = (char*)d_ws;
    u16*   qb   = (u16*)  (ws + OFF_QB);
    u16*   kb   = (u16*)  (ws + OFF_KB);
    u16*   vt   = (u16*)  (ws + OFF_VT);
    float* wf   = (float*)(ws + OFF_WF);
    int*   flag = (int*)  (ws + OFF_FLAG);

    // pick the largest key-split S whose partials fit in ws
    int S = 1;
    for (int cand = 8; cand >= 1; cand >>= 1) {
        size_t need = (size_t)OFF_PO + (size_t)cand * (NN * 64 * 4) +
                      (size_t)cand * (NN * 4);
        if (ws_size >= need) { S = cand; break; }
    }
    float* po = (float*)(ws + OFF_PO);
    float* pl = po + (size_t)S * (NN * 64);
    const int tiles = NN / (128 * S);

    k0_init<<<1, 256, 0, stream>>>(we1, we2, wq, wk, wv, xmod, wf, flag);
    k1_qkv<<<192, 256, 0, stream>>>(xmain, xmod, wf, flag, qb, kb, vt);
    k2_attn<<<384 * S, 256, 0, stream>>>(qb, kb, vt, po, pl, S, tiles);
    k3_norm<<<768, 256, 0, stream>>>((const float4*)po, pl, (float4*)d_out, S);
}

// Round 9
// 131.235 us; speedup vs baseline: 2.1916x; 2.1916x over previous
//
#include <hip/hip_runtime.h>
#include <stdint.h>

// ---------------------------------------------------------------------------
// SelfAttentiveBimodalFusion: MLP(192->16->16) -> Q(8),K(8),V(64) -> full
// N x N attention -> out (N,64).  N = 12288.  fp32 in / fp32 out.
// Validated r5-r8: absmax 9.8e-4 vs thr 2.7e-3.
//
// History: r5 fixed atomics (296 MB atomic writes). r7 fixed occupancy
// (key-split S=8 + prefetch) but was V-gather request-rate-bound (24 KB lane
// stride). r8 fixed coalescing (tiled V + LDS staging) but the uint4 stg[5]
// register round-trip spilled ~6 dwords/thread/iter -> WRITE_SIZE 268 MB of
// scratch writeback -> 185 us.
// r9: staging via __builtin_amdgcn_global_load_lds width=16 (direct
// global->LDS DMA, ZERO staging VGPRs), wave-private LDS double buffer,
// explicit s_waitcnt vmcnt(0) at loop top (compiler does not track the
// builtin's LDS writes vs ds_read). K-tile prefetched in 4 VGPRs.
// Fragment/relabel algebra byte-identical to r5-validated kernel.
// k0 folded into k1 (weights -> LDS per block).
// ---------------------------------------------------------------------------

#define NN 12288

typedef float    f32x16 __attribute__((ext_vector_type(16)));
typedef short    s16x8  __attribute__((ext_vector_type(8)));
typedef unsigned short u16;

#define MFMA_32x32x16_BF16 __builtin_amdgcn_mfma_f32_32x32x16_bf16

// ws layout (bytes)
#define OFF_QB   0u          // N*8*2   = 196608  (bf16, pre-scaled)
#define OFF_KB   196608u     // N*8*2   = 196608  (bf16)
#define OFF_VT   393216u     // 384 tiles * 4608 B = 1769472 (bf16 V, tiled)
#define OFF_PO   2162688u    // S*N*64*4 fp32 O partials; pl follows (S*N*4)

typedef __attribute__((address_space(3))) void lds_void_t;
typedef const __attribute__((address_space(1))) void gbl_void_t;
__device__ __forceinline__ void gld16(const void* g, void* l) {
    __builtin_amdgcn_global_load_lds((gbl_void_t*)g, (lds_void_t*)l, 16, 0, 0);
}

__device__ __forceinline__ float bf2f(u16 s) {
    union { unsigned int u; float f; } c; c.u = ((unsigned int)s) << 16; return c.f;
}
__device__ __forceinline__ u16 f2bf(float f) {
    union { float f; unsigned int u; } c; c.f = f;
    return (u16)((c.u + 0x8000u) >> 16);
}
__device__ __forceinline__ unsigned int pk2(float a, float b) {
    union { float f; unsigned int u; } ca, cb; ca.f = a; cb.f = b;
    return ((ca.u + 0x8000u) >> 16) | ((cb.u + 0x8000u) & 0xffff0000u);
}
__device__ __forceinline__ f32x16 zf16() {
    f32x16 z;
#pragma unroll
    for (int i = 0; i < 16; ++i) z[i] = 0.f;
    return z;
}
__device__ __forceinline__ s16x8 zs8() {
    s16x8 z;
#pragma unroll
    for (int i = 0; i < 8; ++i) z[i] = 0;
    return z;
}

union U8 { s16x8 v; unsigned int u[4]; };

// ---------------- kernel 1: detect + weights->LDS + MLP -> Qb, Kb, Vt -------
// 192 blocks x 256 threads: 64 rows/block, 4 lanes per row.
__global__ __launch_bounds__(256) void k1_qkv(
    const void* __restrict__ xmain, const void* __restrict__ xmod,
    const void* __restrict__ we1, const void* __restrict__ we2,
    const void* __restrict__ wqp, const void* __restrict__ wkp,
    const void* __restrict__ wvp,
    u16* __restrict__ qb, u16* __restrict__ kb, u16* __restrict__ vt)
{
    __shared__ float wf[4608];
    __shared__ int   sflag;
    __shared__ float lh1[64][4][17];
    __shared__ float lh2[64][17];

    const int t = threadIdx.x;
    const int r = t >> 2;            // row in block, 0..63
    const int p = t & 3;             // part, 0..3
    const int row = blockIdx.x * 64 + r;

    // ---- input dtype detection (fp32 mantissa halves look huge as bf16)
    if (t == 0) sflag = 0;
    __syncthreads();
    {
        float v = bf2f(((const u16*)xmod)[2 * t]);
        if (fabsf(v) > 16.f) atomicAdd(&sflag, 1);
    }
    __syncthreads();
    const int isf32 = (sflag > 8);

    // ---- weight conversion into LDS
    const float SCL = 0.51006979f;       // (1/sqrt(8)) * log2(e)
    if (isf32) {
        const float* a1 = (const float*)we1; const float* a2 = (const float*)we2;
        const float* aq = (const float*)wqp; const float* ak = (const float*)wkp;
        const float* av = (const float*)wvp;
        for (int i = t; i < 4608; i += 256) {
            if      (i < 3072) wf[i] = a1[i];
            else if (i < 3328) wf[i] = a2[i - 3072];
            else if (i < 3456) wf[i] = aq[i - 3328] * SCL;
            else if (i < 3584) wf[i] = ak[i - 3456];
            else               wf[i] = av[i - 3584];
        }
    } else {
        const u16* a1 = (const u16*)we1; const u16* a2 = (const u16*)we2;
        const u16* aq = (const u16*)wqp; const u16* ak = (const u16*)wkp;
        const u16* av = (const u16*)wvp;
        for (int i = t; i < 4608; i += 256) {
            if      (i < 3072) wf[i] = bf2f(a1[i]);
            else if (i < 3328) wf[i] = bf2f(a2[i - 3072]);
            else if (i < 3456) wf[i] = bf2f(aq[i - 3328]) * SCL;
            else if (i < 3584) wf[i] = bf2f(ak[i - 3456]);
            else               wf[i] = bf2f(av[i - 3584]);
        }
    }
    __syncthreads();

    const float* __restrict__ W1 = wf;          // [192][16]
    const float* __restrict__ W2 = wf + 3072;   // [16][16]
    const float* __restrict__ Wq = wf + 3328;   // [16][8] pre-scaled
    const float* __restrict__ Wk = wf + 3456;   // [16][8]
    const float* __restrict__ Wv = wf + 3584;   // [16][64]

    float h1p[16];
#pragma unroll
    for (int o = 0; o < 16; ++o) h1p[o] = 0.f;

    if (isf32) {
#pragma unroll
        for (int cc = 0; cc < 12; ++cc) {
            const int c = p + cc * 4;
            float4 xv = (c < 16)
                ? ((const float4*)xmain)[(size_t)row * 16 + c]
                : ((const float4*)xmod)[(size_t)row * 32 + (c - 16)];
            float xs[4] = {xv.x, xv.y, xv.z, xv.w};
#pragma unroll
            for (int j = 0; j < 4; ++j) {
                const float* wr = W1 + (c * 4 + j) * 16;
#pragma unroll
                for (int o = 0; o < 16; ++o) h1p[o] += xs[j] * wr[o];
            }
        }
    } else {
#pragma unroll
        for (int cc = 0; cc < 12; ++cc) {
            const int c = p + cc * 4;
            uint2 xv = (c < 16)
                ? ((const uint2*)xmain)[(size_t)row * 16 + c]
                : ((const uint2*)xmod)[(size_t)row * 32 + (c - 16)];
            float xs[4] = { bf2f((u16)(xv.x & 0xffff)), bf2f((u16)(xv.x >> 16)),
                            bf2f((u16)(xv.y & 0xffff)), bf2f((u16)(xv.y >> 16)) };
#pragma unroll
            for (int j = 0; j < 4; ++j) {
                const float* wr = W1 + (c * 4 + j) * 16;
#pragma unroll
                for (int o = 0; o < 16; ++o) h1p[o] += xs[j] * wr[o];
            }
        }
    }
#pragma unroll
    for (int o = 0; o < 16; ++o) lh1[r][p][o] = h1p[o];
    __syncthreads();

    float h1[16];
#pragma unroll
    for (int o = 0; o < 16; ++o)
        h1[o] = fmaxf(lh1[r][0][o] + lh1[r][1][o] + lh1[r][2][o] + lh1[r][3][o], 0.f);

#pragma unroll
    for (int oo = 0; oo < 4; ++oo) {
        const int o = p * 4 + oo;
        float s = 0.f;
#pragma unroll
        for (int j = 0; j < 16; ++j) s += h1[j] * W2[j * 16 + o];
        lh2[r][o] = fmaxf(s, 0.f);
    }
    __syncthreads();

    float h2[16];
#pragma unroll
    for (int j = 0; j < 16; ++j) h2[j] = lh2[r][j];

    {
        float q0 = 0.f, q1 = 0.f, k0 = 0.f, k1 = 0.f;
        const int o = 2 * p;
#pragma unroll
        for (int j = 0; j < 16; ++j) {
            q0 += h2[j] * Wq[j * 8 + o];
            q1 += h2[j] * Wq[j * 8 + o + 1];
            k0 += h2[j] * Wk[j * 8 + o];
            k1 += h2[j] * Wk[j * 8 + o + 1];
        }
        ((unsigned int*)qb)[(size_t)row * 4 + p] = pk2(q0, q1);
        ((unsigned int*)kb)[(size_t)row * 4 + p] = pk2(k0, k1);
    }

    // V store, key-tiled layout: [tile][c][kk], row stride 36 u16 (72 B)
    const int tI = row >> 5, kk = row & 31;
#pragma unroll
    for (int c16 = 0; c16 < 16; ++c16) {
        const int c = p * 16 + c16;
        float v = 0.f;
#pragma unroll
        for (int j = 0; j < 16; ++j) v += h2[j] * Wv[j * 64 + c];
        vt[(size_t)tI * 2304 + c * 36 + kk] = f2bf(v);
    }
}

// --------------------------- kernel 2: attention partials -------------------
// grid = 384 q-tiles * S key-splits; block = 4 waves; each wave sweeps its
// keys; V tiles staged by global_load_lds DMA into a wave-private LDS
// double buffer (no staging VGPRs, no barriers in the loop).
__global__ __launch_bounds__(256, 4) void k2_attn(
    const u16* __restrict__ qb, const u16* __restrict__ kb,
    const u16* __restrict__ vt,
    float* __restrict__ po, float* __restrict__ pl,
    int nsplit, int tiles)
{
    __shared__ union SM {
        uint4 stage[4][2][288];                      // 36864 B
        struct { float lo[4][64][33]; float ll[4][32]; } ep;  // 34304 B
    } sm;

    const int tid  = threadIdx.x;
    const int lane = tid & 63;
    const int half = lane >> 5;
    const int l31  = lane & 31;
    const int w    = tid >> 6;              // wave 0..3
    const int qt   = blockIdx.x % 384;
    const int sp   = blockIdx.x / 384;
    const int qbase = qt * 32;
    const int key_start = sp * (NN / nsplit) + w * (tiles * 32);
    const int t0 = key_start >> 5;          // first V tile for this wave

    const f32x16 Z = zf16();
    s16x8 qf = zs8();
    if (!half) qf = *(const s16x8*)(qb + (size_t)(qbase + l31) * 8);

    f32x16 acc0 = Z, acc1 = Z;
    float ls = 0.f;

    // stage tile 0 into buf 0 (DMA, coalesced 16-B/lane)
    {
        const char* g = (const char*)vt + (size_t)t0 * 4608 + lane * 16;
#pragma unroll
        for (int j = 0; j < 4; ++j)
            gld16(g + j * 1024, &sm.stage[w][0][j * 64]);
        if (lane < 32)
            gld16(g + 4096, &sm.stage[w][0][256]);
    }
    s16x8 ka_c = *(const s16x8*)(kb + (size_t)(key_start + l31) * 8);

    for (int kt = 0; kt < tiles; ++kt) {
        // wait: current tile's DMA (and ka_c on iter 0) complete
        __builtin_amdgcn_s_waitcnt(0x0F70);          // vmcnt(0)
        const int cb = kt & 1;
        const bool has_next = (kt + 1 < tiles);

        s16x8 ka_n;
        if (has_next) {
            // K prefetch first (VGPR), then next tile's DMA
            ka_n = *(const s16x8*)(kb + (size_t)(key_start + (kt + 1) * 32 + l31) * 8);
            const char* g = (const char*)vt + (size_t)(t0 + kt + 1) * 4608 + lane * 16;
#pragma unroll
            for (int j = 0; j < 4; ++j)
                gld16(g + j * 1024, &sm.stage[w][cb ^ 1][j * 64]);
            if (lane < 32)
                gld16(g + 4096, &sm.stage[w][cb ^ 1][256]);
        }

        // S^T = K.Q^T (Q half1 zero -> one-sided qk pad)
        f32x16 S = MFMA_32x32x16_BF16(ka_c, qf, Z, 0, 0, 0);

        float pr[16];
        float ls0 = 0.f, ls1 = 0.f;
#pragma unroll
        for (int r = 0; r < 8; ++r) {
            pr[r]     = __builtin_amdgcn_exp2f(S[r]);
            pr[r + 8] = __builtin_amdgcn_exp2f(S[r + 8]);
            ls0 += pr[r];
            ls1 += pr[r + 8];
        }
        ls += ls0 + ls1;

        U8 pb0, pb1;
#pragma unroll
        for (int i = 0; i < 4; ++i) {
            pb0.u[i] = pk2(pr[2 * i],     pr[2 * i + 1]);
            pb1.u[i] = pk2(pr[8 + 2 * i], pr[8 + 2 * i + 1]);
        }

        // A-fragments from LDS tile (r5-validated relabeling; u16 units)
        const u16* base = (const u16*)&sm.stage[w][cb][0];
        const u16* r0 = base + l31 * 36 + 4 * half;          // ct=0
        const u16* r1 = base + (32 + l31) * 36 + 4 * half;   // ct=1
        U8 va;
        uint2 x0, x1;
        x0 = *(const uint2*)(r0);       x1 = *(const uint2*)(r0 + 8);
        va.u[0] = x0.x; va.u[1] = x0.y; va.u[2] = x1.x; va.u[3] = x1.y;
        acc0 = MFMA_32x32x16_BF16(va.v, pb0.v, acc0, 0, 0, 0);
        x0 = *(const uint2*)(r1);       x1 = *(const uint2*)(r1 + 8);
        va.u[0] = x0.x; va.u[1] = x0.y; va.u[2] = x1.x; va.u[3] = x1.y;
        acc1 = MFMA_32x32x16_BF16(va.v, pb0.v, acc1, 0, 0, 0);
        x0 = *(const uint2*)(r0 + 16);  x1 = *(const uint2*)(r0 + 24);
        va.u[0] = x0.x; va.u[1] = x0.y; va.u[2] = x1.x; va.u[3] = x1.y;
        acc0 = MFMA_32x32x16_BF16(va.v, pb1.v, acc0, 0, 0, 0);
        x0 = *(const uint2*)(r1 + 16);  x1 = *(const uint2*)(r1 + 24);
        va.u[0] = x0.x; va.u[1] = x0.y; va.u[2] = x1.x; va.u[3] = x1.y;
        acc1 = MFMA_32x32x16_BF16(va.v, pb1.v, acc1, 0, 0, 0);

        if (has_next) ka_c = ka_n;
    }

    // ---- epilogue: reuse staging LDS for the 4-wave reduce ----
    __syncthreads();                        // all waves done with staging

    ls += __shfl_xor(ls, 32, 64);
    if (lane < 32) sm.ep.ll[w][l31] = ls;
#pragma unroll
    for (int r = 0; r < 16; ++r) {
        const int c = (r & 3) + 8 * (r >> 2) + 4 * half;
        sm.ep.lo[w][c][l31]      = acc0[r];
        sm.ep.lo[w][32 + c][l31] = acc1[r];
    }
    __syncthreads();

    const int rq = tid >> 3;                // query 0..31
    const int c0 = (tid & 7) * 8;           // channel base
    float o[8];
#pragma unroll
    for (int j = 0; j < 8; ++j) {
        o[j] = sm.ep.lo[0][c0 + j][rq] + sm.ep.lo[1][c0 + j][rq] +
               sm.ep.lo[2][c0 + j][rq] + sm.ep.lo[3][c0 + j][rq];
    }
    float4* pov = (float4*)(po + (size_t)sp * (NN * 64) +
                            (size_t)(qbase + rq) * 64 + c0);
    pov[0] = make_float4(o[0], o[1], o[2], o[3]);
    pov[1] = make_float4(o[4], o[5], o[6], o[7]);
    if (tid < 32)
        pl[(size_t)sp * NN + qbase + tid] =
            sm.ep.ll[0][tid] + sm.ep.ll[1][tid] + sm.ep.ll[2][tid] + sm.ep.ll[3][tid];
}

// --------------------------- kernel 3: reduce splits + normalize ------------
__global__ __launch_bounds__(256) void k3_norm(
    const float4* __restrict__ po, const float* __restrict__ pl,
    float4* __restrict__ out, int nsplit)
{
    const int i = blockIdx.x * 256 + threadIdx.x;   // 196608 float4s
    const int row = i >> 4;
    float l = 0.f;
    float4 o = make_float4(0.f, 0.f, 0.f, 0.f);
    for (int s = 0; s < nsplit; ++s) {
        l += pl[(size_t)s * NN + row];
        float4 p = po[(size_t)s * (NN * 16) + i];
        o.x += p.x; o.y += p.y; o.z += p.z; o.w += p.w;
    }
    const float rl = 1.0f / l;
    out[i] = make_float4(o.x * rl, o.y * rl, o.z * rl, o.w * rl);
}

// ---------------------------------------------------------------------------
extern "C" void kernel_launch(void* const* d_in, const int* in_sizes, int n_in,
                              void* d_out, int out_size, void* d_ws, size_t ws_size,
                              hipStream_t stream)
{
    const void* xmain = d_in[0];
    const void* xmod  = d_in[1];
    // d_in[2] = xyz (unused by the reference)
    const void* we1   = d_in[3];
    const void* we2   = d_in[4];
    const void* wq    = d_in[5];
    const void* wk    = d_in[6];
    const void* wv    = d_in[7];

    char* ws = (char*)d_ws;
    u16*   qb   = (u16*)  (ws + OFF_QB);
    u16*   kb   = (u16*)  (ws + OFF_KB);
    u16*   vt   = (u16*)  (ws + OFF_VT);

    // pick the largest key-split S whose partials fit in ws
    int S = 1;
    for (int cand = 8; cand >= 1; cand >>= 1) {
        size_t need = (size_t)OFF_PO + (size_t)cand * (NN * 64 * 4) +
                      (size_t)cand * (NN * 4);
        if (ws_size >= need) { S = cand; break; }
    }
    float* po = (float*)(ws + OFF_PO);
    float* pl = po + (size_t)S * (NN * 64);
    const int tiles = NN / (128 * S);

    k1_qkv<<<192, 256, 0, stream>>>(xmain, xmod, we1, we2, wq, wk, wv,
                                    qb, kb, vt);
    k2_attn<<<384 * S, 256, 0, stream>>>(qb, kb, vt, po, pl, S, tiles);
    k3_norm<<<768, 256, 0, stream>>>((const float4*)po, pl, (float4*)d_out, S);
}

// Round 10
// 131.202 us; speedup vs baseline: 2.1922x; 1.0003x over previous
//
#include <hip/hip_runtime.h>
#include <stdint.h>

// ---------------------------------------------------------------------------
// SelfAttentiveBimodalFusion: MLP(192->16->16) -> Q(8),K(8),V(64) -> full
// N x N attention -> out (N,64).  N = 12288.  fp32 in / fp32 out.
// Validated r5-r9: absmax 9.8e-4 vs thr 2.7e-3.
//
// Ladder: r5 killed atomics (296 MB), r7 killed occupancy starvation,
// r8 regressed on scratch spill (268 MB writeback), r9 fixed staging with
// global_load_lds DMA -> k2 = 50 us (VALU-issue ~28 us at 56% busy +
// 679 MB of wave-private L2 DMA reads).
// r10: (a) query-split waves: block = 128 queries / 4 waves sharing ONE
// V-tile double buffer (LDS 9216 B, DMA traffic /4 = 170 MB), barrier-per-
// tile pipeline, S=16 splits -> 1536 blocks = 6 blocks/CU = 24 waves/CU;
// (b) bf16 partials po (out = num/l with l ~1.2e4 -> bf16 partial error
// ~5e-4 on out, in budget) halving k2-write/k3-read traffic;
// (c) v_cvt_pk_bf16_f32 (guarded) for the hot P-pack.
// Fragment/relabel algebra byte-identical to the r5-validated kernel.
// ---------------------------------------------------------------------------

#define NN 12288

typedef float    f32x16 __attribute__((ext_vector_type(16)));
typedef short    s16x8  __attribute__((ext_vector_type(8)));
typedef unsigned short u16;

#define MFMA_32x32x16_BF16 __builtin_amdgcn_mfma_f32_32x32x16_bf16

// ws layout (bytes)
#define OFF_QB   0u          // N*8*2   = 196608  (bf16, pre-scaled)
#define OFF_KB   196608u     // N*8*2   = 196608  (bf16)
#define OFF_VT   393216u     // 384 tiles * 4608 B = 1769472 (bf16 V, tiled)
#define OFF_PO   2162688u    // S*N*64*2 bf16 O partials; pl follows (S*N*4 fp32)

typedef __attribute__((address_space(3))) void lds_void_t;
typedef const __attribute__((address_space(1))) void gbl_void_t;
__device__ __forceinline__ void gld16(const void* g, void* l) {
    __builtin_amdgcn_global_load_lds((gbl_void_t*)g, (lds_void_t*)l, 16, 0, 0);
}

__device__ __forceinline__ float bf2f(u16 s) {
    union { unsigned int u; float f; } c; c.u = ((unsigned int)s) << 16; return c.f;
}
__device__ __forceinline__ u16 f2bf(float f) {
    union { float f; unsigned int u; } c; c.f = f;
    return (u16)((c.u + 0x8000u) >> 16);
}
__device__ __forceinline__ unsigned int pk2(float a, float b) {
    union { float f; unsigned int u; } ca, cb; ca.f = a; cb.f = b;
    return ((ca.u + 0x8000u) >> 16) | ((cb.u + 0x8000u) & 0xffff0000u);
}
// single-instruction packed f32->bf16 where available (gfx950), else manual
__device__ __forceinline__ unsigned int pkbf(float a, float b) {
#if __has_builtin(__builtin_amdgcn_cvt_pk_bf16_f32)
    auto r = __builtin_amdgcn_cvt_pk_bf16_f32(a, b);
    union { decltype(r) v; unsigned int u; } c; c.v = r; return c.u;
#else
    return pk2(a, b);
#endif
}
__device__ __forceinline__ f32x16 zf16() {
    f32x16 z;
#pragma unroll
    for (int i = 0; i < 16; ++i) z[i] = 0.f;
    return z;
}
__device__ __forceinline__ s16x8 zs8() {
    s16x8 z;
#pragma unroll
    for (int i = 0; i < 8; ++i) z[i] = 0;
    return z;
}

union U8 { s16x8 v; unsigned int u[4]; };

// ---------------- kernel 1: detect + weights->LDS + MLP -> Qb, Kb, Vt -------
// (r9-validated, unchanged)
__global__ __launch_bounds__(256) void k1_qkv(
    const void* __restrict__ xmain, const void* __restrict__ xmod,
    const void* __restrict__ we1, const void* __restrict__ we2,
    const void* __restrict__ wqp, const void* __restrict__ wkp,
    const void* __restrict__ wvp,
    u16* __restrict__ qb, u16* __restrict__ kb, u16* __restrict__ vt)
{
    __shared__ float wf[4608];
    __shared__ int   sflag;
    __shared__ float lh1[64][4][17];
    __shared__ float lh2[64][17];

    const int t = threadIdx.x;
    const int r = t >> 2;
    const int p = t & 3;
    const int row = blockIdx.x * 64 + r;

    if (t == 0) sflag = 0;
    __syncthreads();
    {
        float v = bf2f(((const u16*)xmod)[2 * t]);
        if (fabsf(v) > 16.f) atomicAdd(&sflag, 1);
    }
    __syncthreads();
    const int isf32 = (sflag > 8);

    const float SCL = 0.51006979f;       // (1/sqrt(8)) * log2(e)
    if (isf32) {
        const float* a1 = (const float*)we1; const float* a2 = (const float*)we2;
        const float* aq = (const float*)wqp; const float* ak = (const float*)wkp;
        const float* av = (const float*)wvp;
        for (int i = t; i < 4608; i += 256) {
            if      (i < 3072) wf[i] = a1[i];
            else if (i < 3328) wf[i] = a2[i - 3072];
            else if (i < 3456) wf[i] = aq[i - 3328] * SCL;
            else if (i < 3584) wf[i] = ak[i - 3456];
            else               wf[i] = av[i - 3584];
        }
    } else {
        const u16* a1 = (const u16*)we1; const u16* a2 = (const u16*)we2;
        const u16* aq = (const u16*)wqp; const u16* ak = (const u16*)wkp;
        const u16* av = (const u16*)wvp;
        for (int i = t; i < 4608; i += 256) {
            if      (i < 3072) wf[i] = bf2f(a1[i]);
            else if (i < 3328) wf[i] = bf2f(a2[i - 3072]);
            else if (i < 3456) wf[i] = bf2f(aq[i - 3328]) * SCL;
            else if (i < 3584) wf[i] = bf2f(ak[i - 3456]);
            else               wf[i] = bf2f(av[i - 3584]);
        }
    }
    __syncthreads();

    const float* __restrict__ W1 = wf;
    const float* __restrict__ W2 = wf + 3072;
    const float* __restrict__ Wq = wf + 3328;
    const float* __restrict__ Wk = wf + 3456;
    const float* __restrict__ Wv = wf + 3584;

    float h1p[16];
#pragma unroll
    for (int o = 0; o < 16; ++o) h1p[o] = 0.f;

    if (isf32) {
#pragma unroll
        for (int cc = 0; cc < 12; ++cc) {
            const int c = p + cc * 4;
            float4 xv = (c < 16)
                ? ((const float4*)xmain)[(size_t)row * 16 + c]
                : ((const float4*)xmod)[(size_t)row * 32 + (c - 16)];
            float xs[4] = {xv.x, xv.y, xv.z, xv.w};
#pragma unroll
            for (int j = 0; j < 4; ++j) {
                const float* wr = W1 + (c * 4 + j) * 16;
#pragma unroll
                for (int o = 0; o < 16; ++o) h1p[o] += xs[j] * wr[o];
            }
        }
    } else {
#pragma unroll
        for (int cc = 0; cc < 12; ++cc) {
            const int c = p + cc * 4;
            uint2 xv = (c < 16)
                ? ((const uint2*)xmain)[(size_t)row * 16 + c]
                : ((const uint2*)xmod)[(size_t)row * 32 + (c - 16)];
            float xs[4] = { bf2f((u16)(xv.x & 0xffff)), bf2f((u16)(xv.x >> 16)),
                            bf2f((u16)(xv.y & 0xffff)), bf2f((u16)(xv.y >> 16)) };
#pragma unroll
            for (int j = 0; j < 4; ++j) {
                const float* wr = W1 + (c * 4 + j) * 16;
#pragma unroll
                for (int o = 0; o < 16; ++o) h1p[o] += xs[j] * wr[o];
            }
        }
    }
#pragma unroll
    for (int o = 0; o < 16; ++o) lh1[r][p][o] = h1p[o];
    __syncthreads();

    float h1[16];
#pragma unroll
    for (int o = 0; o < 16; ++o)
        h1[o] = fmaxf(lh1[r][0][o] + lh1[r][1][o] + lh1[r][2][o] + lh1[r][3][o], 0.f);

#pragma unroll
    for (int oo = 0; oo < 4; ++oo) {
        const int o = p * 4 + oo;
        float s = 0.f;
#pragma unroll
        for (int j = 0; j < 16; ++j) s += h1[j] * W2[j * 16 + o];
        lh2[r][o] = fmaxf(s, 0.f);
    }
    __syncthreads();

    float h2[16];
#pragma unroll
    for (int j = 0; j < 16; ++j) h2[j] = lh2[r][j];

    {
        float q0 = 0.f, q1 = 0.f, k0 = 0.f, k1 = 0.f;
        const int o = 2 * p;
#pragma unroll
        for (int j = 0; j < 16; ++j) {
            q0 += h2[j] * Wq[j * 8 + o];
            q1 += h2[j] * Wq[j * 8 + o + 1];
            k0 += h2[j] * Wk[j * 8 + o];
            k1 += h2[j] * Wk[j * 8 + o + 1];
        }
        ((unsigned int*)qb)[(size_t)row * 4 + p] = pk2(q0, q1);
        ((unsigned int*)kb)[(size_t)row * 4 + p] = pk2(k0, k1);
    }

    // V store, key-tiled layout: [tile][c][kk], row stride 36 u16 (72 B)
    const int tI = row >> 5, kk = row & 31;
#pragma unroll
    for (int c16 = 0; c16 < 16; ++c16) {
        const int c = p * 16 + c16;
        float v = 0.f;
#pragma unroll
        for (int j = 0; j < 16; ++j) v += h2[j] * Wv[j * 64 + c];
        vt[(size_t)tI * 2304 + c * 36 + kk] = f2bf(v);
    }
}

// --------------------------- kernel 2: attention partials -------------------
// grid = 96 q-blocks * S key-splits; block = 128 queries (4 waves x 32q);
// all waves sweep the same keys sharing ONE DMA-staged V-tile double buffer
// (LDS 9216 B).  One barrier per tile.  bf16 partials out, no atomics.
__global__ __launch_bounds__(256, 6) void k2_attn(
    const u16* __restrict__ qb, const u16* __restrict__ kb,
    const u16* __restrict__ vt,
    u16* __restrict__ po, float* __restrict__ pl,
    int nsplit, int tiles)
{
    __shared__ union SM {
        uint4 stage[2][288];                 // 9216 B V-tile double buffer
        float sf[2304];                      // epilogue transpose (aliased)
    } sm;

    const int tid  = threadIdx.x;
    const int lane = tid & 63;
    const int half = lane >> 5;
    const int l31  = lane & 31;
    const int w    = tid >> 6;               // wave 0..3
    const int qB   = (blockIdx.x % 96) * 128;
    const int sp   = blockIdx.x / 96;
    const int myq  = qB + 32 * w;            // this wave's first query
    const int key_start = sp * (NN / nsplit);
    const int t0 = key_start >> 5;

    const f32x16 Z = zf16();
    s16x8 qf = zs8();
    if (!half) qf = *(const s16x8*)(qb + (size_t)(myq + l31) * 8);

    f32x16 acc0 = Z, acc1 = Z;
    float ls = 0.f;

    // DMA tile 0 -> stage[0]; wave w stages chunk range [72w, 72w+72)
    {
        const char* g = (const char*)vt + (size_t)t0 * 4608 + 1152 * w + lane * 16;
        char* l = (char*)&sm.stage[0][0] + 1152 * w;   // wave-uniform base
        gld16(g, l);
        if (lane < 8) gld16(g + 1024, l + 1024);
    }
    s16x8 ka_c = *(const s16x8*)(kb + (size_t)(key_start + l31) * 8);

    for (int kt = 0; kt < tiles; ++kt) {
        __builtin_amdgcn_s_waitcnt(0x0F70);  // vmcnt(0): my DMA + ka done
        __syncthreads();                     // all waves' DMA visible; prev buf free
        const int cb = kt & 1;
        const bool has_next = (kt + 1 < tiles);

        s16x8 ka_n;
        if (has_next) {
            ka_n = *(const s16x8*)(kb + (size_t)(key_start + (kt + 1) * 32 + l31) * 8);
            const char* g = (const char*)vt + (size_t)(t0 + kt + 1) * 4608
                          + 1152 * w + lane * 16;
            char* l = (char*)&sm.stage[cb ^ 1][0] + 1152 * w;
            gld16(g, l);
            if (lane < 8) gld16(g + 1024, l + 1024);
        }

        // S^T = K.Q^T (Q half1 zero -> one-sided qk pad)
        f32x16 S = MFMA_32x32x16_BF16(ka_c, qf, Z, 0, 0, 0);

        float pr[16];
        float ls0 = 0.f, ls1 = 0.f;
#pragma unroll
        for (int r = 0; r < 8; ++r) {
            pr[r]     = __builtin_amdgcn_exp2f(S[r]);
            pr[r + 8] = __builtin_amdgcn_exp2f(S[r + 8]);
            ls0 += pr[r];
            ls1 += pr[r + 8];
        }
        ls += ls0 + ls1;

        U8 pb0, pb1;
#pragma unroll
        for (int i = 0; i < 4; ++i) {
            pb0.u[i] = pkbf(pr[2 * i],     pr[2 * i + 1]);
            pb1.u[i] = pkbf(pr[8 + 2 * i], pr[8 + 2 * i + 1]);
        }

        // A-fragments from the shared LDS tile (r5-validated relabeling)
        const u16* base = (const u16*)&sm.stage[cb][0];
        const u16* r0 = base + l31 * 36 + 4 * half;          // ct=0
        const u16* r1 = base + (32 + l31) * 36 + 4 * half;   // ct=1
        U8 va;
        uint2 x0, x1;
        x0 = *(const uint2*)(r0);       x1 = *(const uint2*)(r0 + 8);
        va.u[0] = x0.x; va.u[1] = x0.y; va.u[2] = x1.x; va.u[3] = x1.y;
        acc0 = MFMA_32x32x16_BF16(va.v, pb0.v, acc0, 0, 0, 0);
        x0 = *(const uint2*)(r1);       x1 = *(const uint2*)(r1 + 8);
        va.u[0] = x0.x; va.u[1] = x0.y; va.u[2] = x1.x; va.u[3] = x1.y;
        acc1 = MFMA_32x32x16_BF16(va.v, pb0.v, acc1, 0, 0, 0);
        x0 = *(const uint2*)(r0 + 16);  x1 = *(const uint2*)(r0 + 24);
        va.u[0] = x0.x; va.u[1] = x0.y; va.u[2] = x1.x; va.u[3] = x1.y;
        acc0 = MFMA_32x32x16_BF16(va.v, pb1.v, acc0, 0, 0, 0);
        x0 = *(const uint2*)(r1 + 16);  x1 = *(const uint2*)(r1 + 24);
        va.u[0] = x0.x; va.u[1] = x0.y; va.u[2] = x1.x; va.u[3] = x1.y;
        acc1 = MFMA_32x32x16_BF16(va.v, pb1.v, acc1, 0, 0, 0);

        if (has_next) ka_c = ka_n;
    }

    // lanes l and l+32 hold complementary key-halves of query l31's sum
    ls += __shfl_xor(ls, 32, 64);

    // ---- epilogue: per-wave transpose through the (aliased) staging LDS ----
    u16* poS = po + (size_t)sp * (NN * 64);
    for (int j = 0; j < 4; ++j) {
        __syncthreads();
        if (w == j) {
#pragma unroll
            for (int r = 0; r < 16; ++r) {
                const int c = (r & 3) + 8 * (r >> 2) + 4 * half;
                sm.sf[c * 33 + l31]        = acc0[r];
                sm.sf[(32 + c) * 33 + l31] = acc1[r];
            }
            if (lane < 32) sm.sf[2112 + l31] = ls;
        }
        __syncthreads();
        const int rq = tid >> 3;             // query 0..31
        const int c0 = (tid & 7) * 8;        // channel base
        unsigned int u0 = pkbf(sm.sf[(c0 + 0) * 33 + rq], sm.sf[(c0 + 1) * 33 + rq]);
        unsigned int u1 = pkbf(sm.sf[(c0 + 2) * 33 + rq], sm.sf[(c0 + 3) * 33 + rq]);
        unsigned int u2 = pkbf(sm.sf[(c0 + 4) * 33 + rq], sm.sf[(c0 + 5) * 33 + rq]);
        unsigned int u3 = pkbf(sm.sf[(c0 + 6) * 33 + rq], sm.sf[(c0 + 7) * 33 + rq]);
        *(uint4*)(poS + (size_t)(qB + 32 * j + rq) * 64 + c0) =
            make_uint4(u0, u1, u2, u3);
        if (tid < 32)
            pl[(size_t)sp * NN + qB + 32 * j + tid] = sm.sf[2112 + tid];
    }
}

// --------------------------- kernel 3: reduce splits + normalize ------------
__global__ __launch_bounds__(256) void k3_norm(
    const u16* __restrict__ po, const float* __restrict__ pl,
    float4* __restrict__ out, int nsplit)
{
    const int i = blockIdx.x * 256 + threadIdx.x;   // 196608 float4 outputs
    const int row = i >> 4;
    const int c0 = (i & 15) * 4;
    float l = 0.f;
    float o0 = 0.f, o1 = 0.f, o2 = 0.f, o3 = 0.f;
    for (int s = 0; s < nsplit; ++s) {
        l += pl[(size_t)s * NN + row];
        uint2 p = *(const uint2*)(po + (size_t)s * (NN * 64) +
                                  (size_t)row * 64 + c0);
        o0 += bf2f((u16)(p.x & 0xffff)); o1 += bf2f((u16)(p.x >> 16));
        o2 += bf2f((u16)(p.y & 0xffff)); o3 += bf2f((u16)(p.y >> 16));
    }
    const float rl = 1.0f / l;
    out[i] = make_float4(o0 * rl, o1 * rl, o2 * rl, o3 * rl);
}

// ---------------------------------------------------------------------------
extern "C" void kernel_launch(void* const* d_in, const int* in_sizes, int n_in,
                              void* d_out, int out_size, void* d_ws, size_t ws_size,
                              hipStream_t stream)
{
    const void* xmain = d_in[0];
    const void* xmod  = d_in[1];
    // d_in[2] = xyz (unused by the reference)
    const void* we1   = d_in[3];
    const void* we2   = d_in[4];
    const void* wq    = d_in[5];
    const void* wk    = d_in[6];
    const void* wv    = d_in[7];

    char* ws = (char*)d_ws;
    u16*   qb   = (u16*)  (ws + OFF_QB);
    u16*   kb   = (u16*)  (ws + OFF_KB);
    u16*   vt   = (u16*)  (ws + OFF_VT);

    // pick the largest key-split S whose partials fit in ws
    int S = 1;
    for (int cand = 16; cand >= 1; cand >>= 1) {
        size_t need = (size_t)OFF_PO + (size_t)cand * (NN * 64 * 2) +
                      (size_t)cand * (NN * 4);
        if (ws_size >= need) { S = cand; break; }
    }
    u16*   po = (u16*)(ws + OFF_PO);
    float* pl = (float*)(ws + OFF_PO + (size_t)S * (NN * 64 * 2));
    const int tiles = NN / (32 * S);

    k1_qkv<<<192, 256, 0, stream>>>(xmain, xmod, we1, we2, wq, wk, wv,
                                    qb, kb, vt);
    k2_attn<<<96 * S, 256, 0, stream>>>(qb, kb, vt, po, pl, S, tiles);
    k3_norm<<<768, 256, 0, stream>>>(po, pl, (float4*)d_out, S);
}